// Round 18
// baseline (35.772 us; speedup 1.0000x reference)
//
#include <hip/hip_runtime.h>
#include <hip/hip_bf16.h>

// Shapes (fixed by the reference): B=1, M=N=256, O=P=12, C=128, D=32
#define N_ 256
#define M_ 256
#define O_ 12
#define C_ 128
#define D_ 32
#define S2 16          // n-splits (16 n per block-quad)
#define KBROW 393216   // bytes per kb m-row = N*O*D*4

typedef __attribute__((ext_vector_type(8))) short short8;   // 8 x bf16
typedef __attribute__((ext_vector_type(4))) float floatx4;  // MFMA acc

// async global->LDS DMA, 16B/lane: LDS dst = uniform base + lane*16,
// global src is per-lane (m173).
#define GLD16(GSRC, LDST) \
    __builtin_amdgcn_global_load_lds( \
        (const __attribute__((address_space(1))) void*)(GSRC), \
        (__attribute__((address_space(3))) void*)(LDST), 16, 0, 0)

static __device__ __forceinline__ short2 pk2(float a, float b) {
    union { __hip_bfloat162 h; short2 s; } u;
    u.h = __float22bfloat162_rn(make_float2(a, b));  // v_cvt_pk_bf16_f32 RNE
    return u.s;
}

static __device__ __forceinline__ short f2bf(float f) {
    unsigned u = __float_as_uint(f);
    unsigned r = u + 0x7FFFu + ((u >> 16) & 1u);  // RNE
    return (short)(r >> 16);
}

static __device__ __forceinline__ float bf2f(short s) {
    return __uint_as_float(((unsigned)(unsigned short)s) << 16);
}

// ---- prep2: xmm[n][o][c] = x[n,o,c]*mask[n]  and  rk[p,o,c] -------------
__global__ __launch_bounds__(256) void prep2_kernel(
    const float* __restrict__ x, const float* __restrict__ mask,
    const float* __restrict__ fkb, const float* __restrict__ Wr,
    float* __restrict__ xmm, float* __restrict__ rk)
{
    const int b = blockIdx.x;
    const int t = threadIdx.x;
    if (b < 1536) {                       // 1536*256 = 393216 = N*O*C
        const int idx = b * 256 + t;
        const int n = idx / (O_ * C_);
        xmm[idx] = x[idx] * mask[n];
    } else {
        const int idx = (b - 1536) * 256 + t;   // < 18432 = O*O*C
        const int c  = idx & (C_ - 1);
        const int po = idx >> 7;
        const float* f = fkb + po * D_;
        float acc = 0.f;
#pragma unroll
        for (int d = 0; d < D_; ++d) acc = fmaf(f[d], Wr[d * C_ + c], acc);
        rk[idx] = acc;
    }
}

// ---- spatial14: 4-way o-split, 4 barrier domains/CU (R17 proven 35.6) ---
// BYTE-IDENTICAL to round 17 -- do not touch (best known).
__global__ __launch_bounds__(192, 3) void spatial14_kernel(
    const float* __restrict__ kb, const float* __restrict__ xmm,
    const float* __restrict__ Ws, short* __restrict__ part16)
{
    const int mt  = blockIdx.x;   // 0..15
    const int sck = blockIdx.y;   // 0..15
    const int h   = blockIdx.z;   // 0..3 (o-quarter)
    const int t = threadIdx.x;    // 0..191
    const int lane = t & 63;
    const int w = t >> 6;         // wave 0..2; o = h*3 + w
    const int o = h * 3 + w;
    const int l15 = lane & 15;
    const int lk  = lane >> 4;
    const int m0 = mt * 16;
    const int n0 = sck * 16;

    __shared__ __align__(16) char Abuf[2 * 12288];   // 24 KB

    const char* kbc = (const char*)kb;
    // staging: phase tile = 16 rows x 2n x 384B (3 o) = 12KB = 768 chunks.
    // Thread t handles ci = t + g*192 (g=0..3). Chunk ci: r=ci/48,
    // rem=ci%48, ksub=rem/24, q'=rem%24; slot q' of (r,ksub) holds logical
    // chunk q = (q'&~7) | ((q'&7)^(r&7))  (pre-swizzled SOURCE, rule 21).
#define MKSRC(CI) (kbc + (size_t)(m0 + (CI) / 48) * KBROW \
    + (size_t)n0 * 1536 + (size_t)((((CI) % 48) / 24)) * 1536 \
    + (size_t)(h * 384) \
    + (size_t)(((((CI) % 48) % 24 & ~7) \
        | ((((CI) % 48) % 24 & 7) ^ (((CI) / 48) & 7))) * 16))
    const char* s0_ = MKSRC(t);
    const char* s1_ = MKSRC(t + 192);
    const char* s2_ = MKSRC(t + 384);
    const char* s3_ = MKSRC(t + 576);
#undef MKSRC
#define STAGE(BIX, S) { \
    char* db_ = Abuf + (BIX) * 12288 + w * 1024; \
    GLD16(s0_ + (size_t)(S) * 3072, db_); \
    GLD16(s1_ + (size_t)(S) * 3072, db_ + 3072); \
    GLD16(s2_ + (size_t)(S) * 3072, db_ + 6144); \
    GLD16(s3_ + (size_t)(S) * 3072, db_ + 9216); }

    // constant B fragments: wsb[cg][i] = bf16(Ws[lk*8+i][cg*16+l15])
    short8 wsb[8];
#pragma unroll
    for (int cg = 0; cg < 8; ++cg) {
        short8 v;
#pragma unroll
        for (int i = 0; i < 8; ++i)
            v[i] = f2bf(Ws[(lk * 8 + i) * C_ + cg * 16 + l15]);
        wsb[cg] = v;
    }

    // A-read offsets (swizzled): row r=l15 (768B stride), logical chunk
    // q = w*8 + lk*2 + e -> slot w*8 + ((lk*2+e)^(l15&7)); ksub adds 384.
    const int swz = l15 & 7;
    const int oA0 = l15 * 768 + (w * 8 + ((lk * 2)     ^ swz)) * 16;
    const int oA1 = l15 * 768 + (w * 8 + ((lk * 2 + 1) ^ swz)) * 16;

    const float* xb = xmm + ((size_t)n0 * O_ + o) * C_ + l15;

    floatx4 acc[8];
#pragma unroll
    for (int cg = 0; cg < 8; ++cg)
#pragma unroll
        for (int q = 0; q < 4; ++q) acc[cg][q] = 0.f;
    const floatx4 zc = {0.f, 0.f, 0.f, 0.f};

    STAGE(0, 0);

    float xvA[16], xvB[16];   // [ksub*8+cg], double-buffered across phases
#pragma unroll
    for (int k2 = 0; k2 < 2; ++k2)
#pragma unroll
        for (int cg = 0; cg < 8; ++cg)
            xvA[k2 * 8 + cg] = xb[(size_t)k2 * (O_ * C_) + cg * 16];

#define PHASE(S, XC, XN) { \
    asm volatile("s_waitcnt vmcnt(0) lgkmcnt(0)" ::: "memory"); \
    __builtin_amdgcn_s_barrier(); \
    if ((S) + 1 < 8) { \
        STAGE(((S) + 1) & 1, (S) + 1); \
        _Pragma("unroll") \
        for (int k2 = 0; k2 < 2; ++k2) \
            _Pragma("unroll") \
            for (int cg = 0; cg < 8; ++cg) \
                XN[k2 * 8 + cg] = \
                    xb[(size_t)(2 * ((S) + 1) + k2) * (O_ * C_) + cg * 16]; \
    } \
    const char* ab_ = Abuf + ((S) & 1) * 12288; \
    _Pragma("unroll") \
    for (int ksub = 0; ksub < 2; ++ksub) { \
        const floatx4 a0_ = *(const floatx4*)(ab_ + oA0 + ksub * 384); \
        const floatx4 a1_ = *(const floatx4*)(ab_ + oA1 + ksub * 384); \
        union { short8 v; short2 p2[4]; } au_; \
        au_.p2[0] = pk2(a0_[0], a0_[1]); au_.p2[1] = pk2(a0_[2], a0_[3]); \
        au_.p2[2] = pk2(a1_[0], a1_[1]); au_.p2[3] = pk2(a1_[2], a1_[3]); \
        _Pragma("unroll") \
        for (int cg = 0; cg < 8; ++cg) { \
            const floatx4 t_ = __builtin_amdgcn_mfma_f32_16x16x32_bf16( \
                au_.v, wsb[cg], zc, 0, 0, 0); \
            const float xc_ = XC[ksub * 8 + cg]; \
            _Pragma("unroll") \
            for (int q = 0; q < 4; ++q) \
                acc[cg][q] = fmaf(xc_, t_[q], acc[cg][q]); \
        } \
    } }

    PHASE(0, xvA, xvB)
    PHASE(1, xvB, xvA)
    PHASE(2, xvA, xvB)
    PHASE(3, xvB, xvA)
    PHASE(4, xvA, xvB)
    PHASE(5, xvB, xvA)
    PHASE(6, xvA, xvB)
    PHASE(7, xvB, xvA)
#undef PHASE
#undef STAGE

    // C/D: col = lane&15, row = (lane>>4)*4 + reg  [verified rounds 2-17]
    // part16[m][s][o][c], bf16 RNE
#pragma unroll
    for (int cg = 0; cg < 8; ++cg) {
        const int c = cg * 16 + l15;
#pragma unroll
        for (int j = 0; j < 4; ++j) {
            const int m = m0 + lk * 4 + j;
            part16[(((size_t)m * S2 + sck) * O_ + o) * C_ + c] = f2bf(acc[cg][j]);
        }
    }
}

// ---- fiber5: out[m,p,c] = (sum_o y1[o,c] * rk[p,o,c])/12 + bias[c],
//      y1[o,c] = sum_s bf2f(part16[m,s,o,c]).  Grid (M, 2): each block
//      handles one c-half -> 512 blocks = 2/CU (fiber4 had 1/CU,
//      latency-prone). Arithmetic bit-identical to fiber4.
__global__ __launch_bounds__(256) void fiber5_kernel(
    const short* __restrict__ part16, const float* __restrict__ rkv,
    const float* __restrict__ bias, float* __restrict__ out)
{
    const int m  = blockIdx.x;
    const int ch = blockIdx.y;      // c-half: c in [ch*64, ch*64+64)
    const int t = threadIdx.x;
    __shared__ float y1L[O_][64];   // 3 KB

    if (t < 96) {                   // o = t>>3, c-octet = t&7
        const int o  = t >> 3;
        const int cl = (t & 7) * 8;          // local c offset 0..56
        const int c0 = ch * 64 + cl;
        float a[8];
#pragma unroll
        for (int i = 0; i < 8; ++i) a[i] = 0.f;
#pragma unroll
        for (int s = 0; s < S2; ++s) {
            const short8 v = *reinterpret_cast<const short8*>(
                part16 + (((size_t)m * S2 + s) * O_ + o) * C_ + c0);
#pragma unroll
            for (int i = 0; i < 8; ++i) a[i] += bf2f(v[i]);
        }
#pragma unroll
        for (int i = 0; i < 8; ++i) y1L[o][cl + i] = a[i];
    }
    __syncthreads();

#pragma unroll
    for (int k = t; k < O_ * 64; k += 256) {   // 768 elems, 3 per thread
        const int p  = k >> 6;
        const int cl = k & 63;
        const int c  = ch * 64 + cl;
        float a = 0.f;
#pragma unroll
        for (int o = 0; o < O_; ++o)
            a = fmaf(y1L[o][cl], rkv[(p * O_ + o) * C_ + c], a);
        out[((size_t)m * O_ + p) * C_ + c] = a * (1.f / 12.f) + bias[c];
    }
}

// ---------------- fallback (round-1) path, used only if ws is small ------
__global__ __launch_bounds__(256) void spatial_old_kernel(
    const float* __restrict__ x, const float* __restrict__ kb,
    const float* __restrict__ mask, const float* __restrict__ Ws,
    float* __restrict__ y1)
{
    const int bid = blockIdx.x;
    const int m = bid / O_, o = bid % O_;
    const int tid = threadIdx.x;
    const int h = tid >> 7, c = tid & (C_ - 1);
    __shared__ float kbs[2][8][D_];
    __shared__ float msk[N_];
    __shared__ float Ts[2][D_][C_];
    msk[tid] = mask[tid];
    float T[D_];
#pragma unroll
    for (int d = 0; d < D_; ++d) T[d] = 0.f;
    const float* kb_mo = kb + (size_t)m * (N_ * O_ * D_) + o * D_;
    const int j_ld = c >> 4, d_ld = (c & 15) * 2;
    for (int chunk = 0; chunk < 16; ++chunk) {
        const int n0 = h * 128 + chunk * 8;
        __syncthreads();
        float2 v = *reinterpret_cast<const float2*>(
            kb_mo + (size_t)(n0 + j_ld) * (O_ * D_) + d_ld);
        kbs[h][j_ld][d_ld] = v.x;
        kbs[h][j_ld][d_ld + 1] = v.y;
        __syncthreads();
#pragma unroll
        for (int j = 0; j < 8; ++j) {
            const int n = n0 + j;
            const float xv = x[(n * O_ + o) * C_ + c] * msk[n];
#pragma unroll
            for (int d = 0; d < D_; ++d) T[d] = fmaf(kbs[h][j][d], xv, T[d]);
        }
    }
#pragma unroll
    for (int d = 0; d < D_; ++d) Ts[h][d][c] = T[d];
    __syncthreads();
    if (h == 0) {
        float a = 0.f;
#pragma unroll
        for (int d = 0; d < D_; ++d)
            a = fmaf(Ts[0][d][c] + Ts[1][d][c], Ws[d * C_ + c], a);
        y1[((size_t)m * O_ + o) * C_ + c] = a;
    }
}

__global__ __launch_bounds__(256) void fiber_old_kernel(
    const float* __restrict__ y1, const float* __restrict__ rkv,
    const float* __restrict__ bias, float* __restrict__ out)
{
    int idx = blockIdx.x * 256 + threadIdx.x;
    if (idx >= M_ * O_ * C_) return;
    int c = idx & (C_ - 1);
    int p = (idx >> 7) % O_;
    int m = idx / (O_ * C_);
    float a = 0.f;
#pragma unroll
    for (int o = 0; o < O_; ++o)
        a = fmaf(y1[(m * O_ + o) * C_ + c], rkv[(p * O_ + o) * C_ + c], a);
    out[idx] = a * (1.0f / 12.0f) + bias[c];
}

__global__ __launch_bounds__(256) void rot_proj_kernel(
    const float* __restrict__ fkb, const float* __restrict__ Wr,
    float* __restrict__ rk)
{
    int idx = blockIdx.x * 256 + threadIdx.x;
    if (idx >= O_ * O_ * C_) return;
    int c  = idx & (C_ - 1);
    int po = idx >> 7;
    const float* f = fkb + po * D_;
    float acc = 0.f;
#pragma unroll
    for (int d = 0; d < D_; ++d) acc = fmaf(f[d], Wr[d * C_ + c], acc);
    rk[idx] = acc;
}

extern "C" void kernel_launch(void* const* d_in, const int* in_sizes, int n_in,
                              void* d_out, int out_size, void* d_ws, size_t ws_size,
                              hipStream_t stream)
{
    const float* x    = (const float*)d_in[0];  // (1,256,12,128)
    const float* kb   = (const float*)d_in[1];  // (1,256,256,12,32)
    const float* fkb  = (const float*)d_in[2];  // (12,12,32)
    const float* mask = (const float*)d_in[3];  // (1,256)
    const float* Wsp  = (const float*)d_in[4];  // (32,128)
    const float* Wrt  = (const float*)d_in[5];  // (32,128)
    const float* bias = (const float*)d_in[6];  // (128,)
    float* out = (float*)d_out;                 // (1,256,12,128)

    const size_t RK_F    = (size_t)O_ * O_ * C_;        // 18432 floats
    const size_t PART_E  = (size_t)M_ * S2 * O_ * C_;   // 6291456 bf16
    const size_t XMM_F   = (size_t)N_ * O_ * C_;        // 393216 floats
    const size_t need    = RK_F * 4 + PART_E * 2 + XMM_F * 4;  // ~14.2 MB

    float* rk = (float*)d_ws;

    if (ws_size >= need) {
        short* part16 = (short*)(rk + RK_F);
        float* xmm    = (float*)(part16 + PART_E);
        prep2_kernel<<<1536 + (O_ * O_ * C_) / 256, 256, 0, stream>>>(
            x, mask, fkb, Wrt, xmm, rk);
        spatial14_kernel<<<dim3(16, 16, 4), 192, 0, stream>>>(
            kb, xmm, Wsp, part16);
        fiber5_kernel<<<dim3(M_, 2), 256, 0, stream>>>(part16, rk, bias, out);
    } else {
        float* y1 = rk + RK_F;
        rot_proj_kernel<<<(O_ * O_ * C_ + 255) / 256, 256, 0, stream>>>(fkb, Wrt, rk);
        spatial_old_kernel<<<M_ * O_, 256, 0, stream>>>(x, kb, mask, Wsp, y1);
        fiber_old_kernel<<<(M_ * O_ * C_ + 255) / 256, 256, 0, stream>>>(y1, rk, bias, out);
    }
}

// Round 19
// 34.982 us; speedup vs baseline: 1.0226x; 1.0226x over previous
//
#include <hip/hip_runtime.h>
#include <hip/hip_bf16.h>

// Shapes (fixed by the reference): B=1, M=N=256, O=P=12, C=128, D=32
#define N_ 256
#define M_ 256
#define O_ 12
#define C_ 128
#define D_ 32
#define S2 16          // n-splits (16 n per block-quad)
#define KBROW 393216   // bytes per kb m-row = N*O*D*4

typedef __attribute__((ext_vector_type(8))) short short8;   // 8 x bf16
typedef __attribute__((ext_vector_type(4))) float floatx4;  // MFMA acc

// async global->LDS DMA, 16B/lane: LDS dst = uniform base + lane*16,
// global src is per-lane (m173).
#define GLD16(GSRC, LDST) \
    __builtin_amdgcn_global_load_lds( \
        (const __attribute__((address_space(1))) void*)(GSRC), \
        (__attribute__((address_space(3))) void*)(LDST), 16, 0, 0)

static __device__ __forceinline__ short2 pk2(float a, float b) {
    union { __hip_bfloat162 h; short2 s; } u;
    u.h = __float22bfloat162_rn(make_float2(a, b));  // v_cvt_pk_bf16_f32 RNE
    return u.s;
}

static __device__ __forceinline__ short f2bf(float f) {
    unsigned u = __float_as_uint(f);
    unsigned r = u + 0x7FFFu + ((u >> 16) & 1u);  // RNE
    return (short)(r >> 16);
}

static __device__ __forceinline__ float bf2f(short s) {
    return __uint_as_float(((unsigned)(unsigned short)s) << 16);
}

// ---- prep2: xmm[n][o][c] = x[n,o,c]*mask[n]  and  rk[p,o,c] -------------
__global__ __launch_bounds__(256) void prep2_kernel(
    const float* __restrict__ x, const float* __restrict__ mask,
    const float* __restrict__ fkb, const float* __restrict__ Wr,
    float* __restrict__ xmm, float* __restrict__ rk)
{
    const int b = blockIdx.x;
    const int t = threadIdx.x;
    if (b < 1536) {                       // 1536*256 = 393216 = N*O*C
        const int idx = b * 256 + t;
        const int n = idx / (O_ * C_);
        xmm[idx] = x[idx] * mask[n];
    } else {
        const int idx = (b - 1536) * 256 + t;   // < 18432 = O*O*C
        const int c  = idx & (C_ - 1);
        const int po = idx >> 7;
        const float* f = fkb + po * D_;
        float acc = 0.f;
#pragma unroll
        for (int d = 0; d < D_; ++d) acc = fmaf(f[d], Wr[d * C_ + c], acc);
        rk[idx] = acc;
    }
}

// ---- spatial15: BARRIER-FREE wave-private DMA pipeline ------------------
// Same o-split/tile/numerics as R17's spatial14 (proven 35.6 us), but each
// wave stages ONLY its own o-slice (16 rows x 2n x 128B = 4KB, 4 GLD16)
// into wave-private LDS double buffers and waits vmcnt(0) on its OWN queue.
// No s_barrier anywhere: 12 independent wave pipelines per CU -- any
// wave's drain is covered by the other 11 (m114 wave-level overlap), vs
// the barrier convoy that synchronized all waves into draining together.
// In-wave WAR safe: phase s-1's MFMAs can't issue until their ds_reads
// landed (compiler lgkmcnt); STAGE(s+1) issues after them in program order.
__global__ __launch_bounds__(192, 3) void spatial15_kernel(
    const float* __restrict__ kb, const float* __restrict__ xmm,
    const float* __restrict__ Ws, short* __restrict__ part16)
{
    const int mt  = blockIdx.x;   // 0..15
    const int sck = blockIdx.y;   // 0..15
    const int h   = blockIdx.z;   // 0..3 (o-quarter)
    const int t = threadIdx.x;    // 0..191
    const int lane = t & 63;
    const int w = t >> 6;         // wave 0..2; o = h*3 + w
    const int o = h * 3 + w;
    const int l15 = lane & 15;
    const int lk  = lane >> 4;
    const int m0 = mt * 16;
    const int n0 = sck * 16;

    __shared__ __align__(16) char Abuf[3 * 2 * 4096];   // 24 KB
    char* wbuf = Abuf + w * 8192;    // wave-private 2 x 4KB

    const char* kbc = (const char*)kb;
    // wave-private staging: phase tile = 16 rows x 2n x 128B = 4KB =
    // 256 chunks(16B); GLD16 g covers ci = lane + g*64. Chunk ci:
    // r = ci>>4, ksub = (ci>>3)&1, q' = ci&7; slot q' of (r,ksub) holds
    // logical chunk q = q'^(r&7)  (pre-swizzled SOURCE, rule 21).
    // Global byte: (m0+r)*KBROW + (n0+2S+ksub)*1536 + o*128 + q*16.
#define MKSRC(CI) (kbc + (size_t)(m0 + ((CI) >> 4)) * KBROW \
    + (size_t)n0 * 1536 + (size_t)(((CI) >> 3) & 1) * 1536 \
    + (size_t)(o * 128) \
    + (size_t)((((CI) & 7) ^ (((CI) >> 4) & 7)) * 16))
    const char* s0_ = MKSRC(lane);
    const char* s1_ = MKSRC(lane + 64);
    const char* s2_ = MKSRC(lane + 128);
    const char* s3_ = MKSRC(lane + 192);
#undef MKSRC
    // LDS linear in ci: addr = ci*16 (r stride 256B, ksub stride 128B).
#define STAGE(BIX, S) { \
    char* db_ = wbuf + (BIX) * 4096; \
    GLD16(s0_ + (size_t)(S) * 3072, db_); \
    GLD16(s1_ + (size_t)(S) * 3072, db_ + 1024); \
    GLD16(s2_ + (size_t)(S) * 3072, db_ + 2048); \
    GLD16(s3_ + (size_t)(S) * 3072, db_ + 3072); }

    // constant B fragments: wsb[cg][i] = bf16(Ws[lk*8+i][cg*16+l15])
    short8 wsb[8];
#pragma unroll
    for (int cg = 0; cg < 8; ++cg) {
        short8 v;
#pragma unroll
        for (int i = 0; i < 8; ++i)
            v[i] = f2bf(Ws[(lk * 8 + i) * C_ + cg * 16 + l15]);
        wsb[cg] = v;
    }

    // A-read offsets (swizzled): row r=l15 (256B stride), logical chunk
    // q = lk*2 + e -> slot (lk*2+e)^(l15&7); ksub adds 128B.
    const int swz = l15 & 7;
    const int oA0 = l15 * 256 + (((lk * 2)     ^ swz) * 16);
    const int oA1 = l15 * 256 + (((lk * 2 + 1) ^ swz) * 16);

    const float* xb = xmm + ((size_t)n0 * O_ + o) * C_ + l15;

    floatx4 acc[8];
#pragma unroll
    for (int cg = 0; cg < 8; ++cg)
#pragma unroll
        for (int q = 0; q < 4; ++q) acc[cg][q] = 0.f;
    const floatx4 zc = {0.f, 0.f, 0.f, 0.f};

    STAGE(0, 0);

    float xvA[16], xvB[16];   // [ksub*8+cg], double-buffered across phases
#pragma unroll
    for (int k2 = 0; k2 < 2; ++k2)
#pragma unroll
        for (int cg = 0; cg < 8; ++cg)
            xvA[k2 * 8 + cg] = xb[(size_t)k2 * (O_ * C_) + cg * 16];

#define PHASE(S, XC, XN) { \
    asm volatile("s_waitcnt vmcnt(0)" ::: "memory"); \
    if ((S) + 1 < 8) { \
        STAGE(((S) + 1) & 1, (S) + 1); \
        _Pragma("unroll") \
        for (int k2 = 0; k2 < 2; ++k2) \
            _Pragma("unroll") \
            for (int cg = 0; cg < 8; ++cg) \
                XN[k2 * 8 + cg] = \
                    xb[(size_t)(2 * ((S) + 1) + k2) * (O_ * C_) + cg * 16]; \
    } \
    const char* ab_ = wbuf + ((S) & 1) * 4096; \
    _Pragma("unroll") \
    for (int ksub = 0; ksub < 2; ++ksub) { \
        const floatx4 a0_ = *(const floatx4*)(ab_ + oA0 + ksub * 128); \
        const floatx4 a1_ = *(const floatx4*)(ab_ + oA1 + ksub * 128); \
        union { short8 v; short2 p2[4]; } au_; \
        au_.p2[0] = pk2(a0_[0], a0_[1]); au_.p2[1] = pk2(a0_[2], a0_[3]); \
        au_.p2[2] = pk2(a1_[0], a1_[1]); au_.p2[3] = pk2(a1_[2], a1_[3]); \
        _Pragma("unroll") \
        for (int cg = 0; cg < 8; ++cg) { \
            const floatx4 t_ = __builtin_amdgcn_mfma_f32_16x16x32_bf16( \
                au_.v, wsb[cg], zc, 0, 0, 0); \
            const float xc_ = XC[ksub * 8 + cg]; \
            _Pragma("unroll") \
            for (int q = 0; q < 4; ++q) \
                acc[cg][q] = fmaf(xc_, t_[q], acc[cg][q]); \
        } \
    } }

    PHASE(0, xvA, xvB)
    PHASE(1, xvB, xvA)
    PHASE(2, xvA, xvB)
    PHASE(3, xvB, xvA)
    PHASE(4, xvA, xvB)
    PHASE(5, xvB, xvA)
    PHASE(6, xvA, xvB)
    PHASE(7, xvB, xvA)
#undef PHASE
#undef STAGE

    // C/D: col = lane&15, row = (lane>>4)*4 + reg  [verified rounds 2-18]
    // part16[m][s][o][c], bf16 RNE
#pragma unroll
    for (int cg = 0; cg < 8; ++cg) {
        const int c = cg * 16 + l15;
#pragma unroll
        for (int j = 0; j < 4; ++j) {
            const int m = m0 + lk * 4 + j;
            part16[(((size_t)m * S2 + sck) * O_ + o) * C_ + c] = f2bf(acc[cg][j]);
        }
    }
}

// ---- fiber4: out[m,p,c] = (sum_o y1[o,c] * rk[p,o,c])/12 + bias[c],
//      y1[o,c] = sum_s bf2f(part16[m,s,o,c])   (R17 proven config)
__global__ __launch_bounds__(256) void fiber4_kernel(
    const short* __restrict__ part16, const float* __restrict__ rkv,
    const float* __restrict__ bias, float* __restrict__ out)
{
    const int m = blockIdx.x;
    const int t = threadIdx.x;
    __shared__ float y1L[O_][C_];   // 6 KB

    if (t < 192) {                  // o = t>>4, c-octet = t&15
        const int o  = t >> 4;
        const int c0 = (t & 15) * 8;
        float a[8];
#pragma unroll
        for (int i = 0; i < 8; ++i) a[i] = 0.f;
#pragma unroll
        for (int s = 0; s < S2; ++s) {
            const short8 v = *reinterpret_cast<const short8*>(
                part16 + (((size_t)m * S2 + s) * O_ + o) * C_ + c0);
#pragma unroll
            for (int i = 0; i < 8; ++i) a[i] += bf2f(v[i]);
        }
#pragma unroll
        for (int i = 0; i < 8; ++i) y1L[o][c0 + i] = a[i];
    }
    __syncthreads();

#pragma unroll
    for (int k = t; k < O_ * C_; k += 256) {
        const int p = k >> 7;
        const int c = k & (C_ - 1);
        float a = 0.f;
#pragma unroll
        for (int o = 0; o < O_; ++o)
            a = fmaf(y1L[o][c], rkv[(p * O_ + o) * C_ + c], a);
        out[((size_t)m * O_ + p) * C_ + c] = a * (1.f / 12.f) + bias[c];
    }
}

// ---------------- fallback (round-1) path, used only if ws is small ------
__global__ __launch_bounds__(256) void spatial_old_kernel(
    const float* __restrict__ x, const float* __restrict__ kb,
    const float* __restrict__ mask, const float* __restrict__ Ws,
    float* __restrict__ y1)
{
    const int bid = blockIdx.x;
    const int m = bid / O_, o = bid % O_;
    const int tid = threadIdx.x;
    const int h = tid >> 7, c = tid & (C_ - 1);
    __shared__ float kbs[2][8][D_];
    __shared__ float msk[N_];
    __shared__ float Ts[2][D_][C_];
    msk[tid] = mask[tid];
    float T[D_];
#pragma unroll
    for (int d = 0; d < D_; ++d) T[d] = 0.f;
    const float* kb_mo = kb + (size_t)m * (N_ * O_ * D_) + o * D_;
    const int j_ld = c >> 4, d_ld = (c & 15) * 2;
    for (int chunk = 0; chunk < 16; ++chunk) {
        const int n0 = h * 128 + chunk * 8;
        __syncthreads();
        float2 v = *reinterpret_cast<const float2*>(
            kb_mo + (size_t)(n0 + j_ld) * (O_ * D_) + d_ld);
        kbs[h][j_ld][d_ld] = v.x;
        kbs[h][j_ld][d_ld + 1] = v.y;
        __syncthreads();
#pragma unroll
        for (int j = 0; j < 8; ++j) {
            const int n = n0 + j;
            const float xv = x[(n * O_ + o) * C_ + c] * msk[n];
#pragma unroll
            for (int d = 0; d < D_; ++d) T[d] = fmaf(kbs[h][j][d], xv, T[d]);
        }
    }
#pragma unroll
    for (int d = 0; d < D_; ++d) Ts[h][d][c] = T[d];
    __syncthreads();
    if (h == 0) {
        float a = 0.f;
#pragma unroll
        for (int d = 0; d < D_; ++d)
            a = fmaf(Ts[0][d][c] + Ts[1][d][c], Ws[d * C_ + c], a);
        y1[((size_t)m * O_ + o) * C_ + c] = a;
    }
}

__global__ __launch_bounds__(256) void fiber_old_kernel(
    const float* __restrict__ y1, const float* __restrict__ rkv,
    const float* __restrict__ bias, float* __restrict__ out)
{
    int idx = blockIdx.x * 256 + threadIdx.x;
    if (idx >= M_ * O_ * C_) return;
    int c = idx & (C_ - 1);
    int p = (idx >> 7) % O_;
    int m = idx / (O_ * C_);
    float a = 0.f;
#pragma unroll
    for (int o = 0; o < O_; ++o)
        a = fmaf(y1[(m * O_ + o) * C_ + c], rkv[(p * O_ + o) * C_ + c], a);
    out[idx] = a * (1.0f / 12.0f) + bias[c];
}

__global__ __launch_bounds__(256) void rot_proj_kernel(
    const float* __restrict__ fkb, const float* __restrict__ Wr,
    float* __restrict__ rk)
{
    int idx = blockIdx.x * 256 + threadIdx.x;
    if (idx >= O_ * O_ * C_) return;
    int c  = idx & (C_ - 1);
    int po = idx >> 7;
    const float* f = fkb + po * D_;
    float acc = 0.f;
#pragma unroll
    for (int d = 0; d < D_; ++d) acc = fmaf(f[d], Wr[d * C_ + c], acc);
    rk[idx] = acc;
}

extern "C" void kernel_launch(void* const* d_in, const int* in_sizes, int n_in,
                              void* d_out, int out_size, void* d_ws, size_t ws_size,
                              hipStream_t stream)
{
    const float* x    = (const float*)d_in[0];  // (1,256,12,128)
    const float* kb   = (const float*)d_in[1];  // (1,256,256,12,32)
    const float* fkb  = (const float*)d_in[2];  // (12,12,32)
    const float* mask = (const float*)d_in[3];  // (1,256)
    const float* Wsp  = (const float*)d_in[4];  // (32,128)
    const float* Wrt  = (const float*)d_in[5];  // (32,128)
    const float* bias = (const float*)d_in[6];  // (128,)
    float* out = (float*)d_out;                 // (1,256,12,128)

    const size_t RK_F    = (size_t)O_ * O_ * C_;        // 18432 floats
    const size_t PART_E  = (size_t)M_ * S2 * O_ * C_;   // 6291456 bf16
    const size_t XMM_F   = (size_t)N_ * O_ * C_;        // 393216 floats
    const size_t need    = RK_F * 4 + PART_E * 2 + XMM_F * 4;  // ~14.2 MB

    float* rk = (float*)d_ws;

    if (ws_size >= need) {
        short* part16 = (short*)(rk + RK_F);
        float* xmm    = (float*)(part16 + PART_E);
        prep2_kernel<<<1536 + (O_ * O_ * C_) / 256, 256, 0, stream>>>(
            x, mask, fkb, Wrt, xmm, rk);
        spatial15_kernel<<<dim3(16, 16, 4), 192, 0, stream>>>(
            kb, xmm, Wsp, part16);
        fiber4_kernel<<<M_, 256, 0, stream>>>(part16, rk, bias, out);
    } else {
        float* y1 = rk + RK_F;
        rot_proj_kernel<<<(O_ * O_ * C_ + 255) / 256, 256, 0, stream>>>(fkb, Wrt, rk);
        spatial_old_kernel<<<M_ * O_, 256, 0, stream>>>(x, kb, mask, Wsp, y1);
        fiber_old_kernel<<<(M_ * O_ * C_ + 255) / 256, 256, 0, stream>>>(y1, rk, bias, out);
    }
}